// Round 1
// baseline (198.042 us; speedup 1.0000x reference)
//
#include <hip/hip_runtime.h>

// SSIM loss, fused. Input: enhanced, target fp32 [16,3,512,512]. Output: scalar fp32.
// Separable 7-tap Gaussian (sigma=1.5) over 5 channels (x, y, x^2, y^2, x*y),
// zero padding, SSIM map, global mean, out = 1 - mean.

#define TILE_W 64
#define TILE_H 16
#define HALO 3
#define IN_W (TILE_W + 2 * HALO)   // 70
#define IN_H (TILE_H + 2 * HALO)   // 22
#define IN_STRIDE 72               // pad to avoid pathological strides
#define IMG_H 512
#define IMG_W 512
#define NPLANES 48                 // 16 * 3
#define SSIM_C1 1.0e-4f
#define SSIM_C2 9.0e-4f

__device__ __constant__ float c_g[7] = {
    0.03663284536f, 0.11128076166f, 0.21674531251f, 0.27068216094f,
    0.21674531251f, 0.11128076166f, 0.03663284536f};

__global__ __launch_bounds__(256) void ssim_tile_kernel(
    const float* __restrict__ x, const float* __restrict__ y,
    float* __restrict__ partial) {
  __shared__ float sx[IN_H][IN_STRIDE];
  __shared__ float sy[IN_H][IN_STRIDE];
  __shared__ float h1[IN_H][TILE_W];
  __shared__ float h2[IN_H][TILE_W];
  __shared__ float hxx[IN_H][TILE_W];
  __shared__ float hyy[IN_H][TILE_W];
  __shared__ float hxy[IN_H][TILE_W];

  const int tid = threadIdx.y * 64 + threadIdx.x;
  const int plane = blockIdx.z;
  const float* __restrict__ xp = x + (size_t)plane * IMG_H * IMG_W;
  const float* __restrict__ yp = y + (size_t)plane * IMG_H * IMG_W;
  const int x0 = blockIdx.x * TILE_W - HALO;
  const int y0 = blockIdx.y * TILE_H - HALO;

  // Stage halo tile (zero padding at plane borders).
  for (int i = tid; i < IN_H * IN_W; i += 256) {
    const int r = i / IN_W, c = i - r * IN_W;
    const int gx = x0 + c, gy = y0 + r;
    float xv = 0.f, yv = 0.f;
    if (gx >= 0 && gx < IMG_W && gy >= 0 && gy < IMG_H) {
      const int idx = gy * IMG_W + gx;
      xv = xp[idx];
      yv = yp[idx];
    }
    sx[r][c] = xv;
    sy[r][c] = yv;
  }
  __syncthreads();

  // Horizontal 7-tap pass over 5 channels.
  for (int i = tid; i < IN_H * TILE_W; i += 256) {
    const int r = i >> 6, c = i & 63;
    float s1 = 0.f, s2 = 0.f, sxx = 0.f, syy = 0.f, sxy = 0.f;
#pragma unroll
    for (int k = 0; k < 7; ++k) {
      const float gk = c_g[k];
      const float xv = sx[r][c + k];
      const float yv = sy[r][c + k];
      s1 += gk * xv;
      s2 += gk * yv;
      sxx += gk * (xv * xv);
      syy += gk * (yv * yv);
      sxy += gk * (xv * yv);
    }
    h1[r][c] = s1;
    h2[r][c] = s2;
    hxx[r][c] = sxx;
    hyy[r][c] = syy;
    hxy[r][c] = sxy;
  }
  __syncthreads();

  // Vertical 7-tap pass + SSIM map + per-thread accumulation.
  float acc = 0.f;
  for (int r = threadIdx.y; r < TILE_H; r += 4) {
    float mu1 = 0.f, mu2 = 0.f, exx = 0.f, eyy = 0.f, exy = 0.f;
#pragma unroll
    for (int k = 0; k < 7; ++k) {
      const float gk = c_g[k];
      mu1 += gk * h1[r + k][threadIdx.x];
      mu2 += gk * h2[r + k][threadIdx.x];
      exx += gk * hxx[r + k][threadIdx.x];
      eyy += gk * hyy[r + k][threadIdx.x];
      exy += gk * hxy[r + k][threadIdx.x];
    }
    const float mu1sq = mu1 * mu1;
    const float mu2sq = mu2 * mu2;
    const float mu12 = mu1 * mu2;
    const float sig1 = exx - mu1sq;
    const float sig2 = eyy - mu2sq;
    const float sig12 = exy - mu12;
    const float num = (2.f * mu12 + SSIM_C1) * (2.f * sig12 + SSIM_C2);
    const float den = (mu1sq + mu2sq + SSIM_C1) * (sig1 + sig2 + SSIM_C2);
    acc += num / den;
  }

  // Block reduction: wave64 shuffle tree, then LDS across 4 waves.
#pragma unroll
  for (int off = 32; off > 0; off >>= 1) acc += __shfl_down(acc, off, 64);
  __shared__ float wsum[4];
  if ((tid & 63) == 0) wsum[tid >> 6] = acc;
  __syncthreads();
  if (tid == 0) {
    const float s = wsum[0] + wsum[1] + wsum[2] + wsum[3];
    partial[(size_t)blockIdx.z * gridDim.x * gridDim.y +
            (size_t)blockIdx.y * gridDim.x + blockIdx.x] = s;
  }
}

__global__ __launch_bounds__(256) void ssim_reduce_kernel(
    const float* __restrict__ partial, int n, float* __restrict__ out) {
  float acc = 0.f;
  for (int i = threadIdx.x; i < n; i += 256) acc += partial[i];
#pragma unroll
  for (int off = 32; off > 0; off >>= 1) acc += __shfl_down(acc, off, 64);
  __shared__ float wsum[4];
  if ((threadIdx.x & 63) == 0) wsum[threadIdx.x >> 6] = acc;
  __syncthreads();
  if (threadIdx.x == 0) {
    const float s = wsum[0] + wsum[1] + wsum[2] + wsum[3];
    out[0] = 1.f - s * (1.f / (float)(NPLANES * IMG_H * IMG_W));
  }
}

extern "C" void kernel_launch(void* const* d_in, const int* in_sizes, int n_in,
                              void* d_out, int out_size, void* d_ws, size_t ws_size,
                              hipStream_t stream) {
  const float* enhanced = (const float*)d_in[0];
  const float* target = (const float*)d_in[1];
  float* out = (float*)d_out;
  float* partial = (float*)d_ws;

  dim3 grid(IMG_W / TILE_W, IMG_H / TILE_H, NPLANES);  // 8 x 32 x 48 = 12288
  dim3 block(64, 4, 1);
  ssim_tile_kernel<<<grid, block, 0, stream>>>(enhanced, target, partial);

  const int nblocks = (IMG_W / TILE_W) * (IMG_H / TILE_H) * NPLANES;
  ssim_reduce_kernel<<<1, 256, 0, stream>>>(partial, nblocks, out);
}